// Round 1
// baseline (3183.398 us; speedup 1.0000x reference)
//
#include <hip/hip_runtime.h>
#include <math.h>

#define HID   128
#define NNODE 50000
#define NEDGE 800000
#define EB    64          // edges (or nodes) per block
#define PF    260         // feat pitch in dwords (260 % 8 == 4 -> 8-way worst conflict; 16B aligned)
#define PB    132         // buffer pitch in dwords (132 % 8 == 4)

__device__ __forceinline__ float silu_f(float x) {
    return x / (1.0f + __expf(-x));
}

// Panel GEMM: out[e][jb..jb+31] += src[e][0..4*NC) @ W[0..4*NC)[jb..jb+31]
// lane = e (divergent), jb wave-uniform -> W loads become s_load (scalar pipe).
// Requires src row pitch >= 4*(NC+1) dwords (we read one chunk ahead).
template<int NC>
__device__ __forceinline__ void panel_fma(const float* __restrict__ src, int pitch_dw, int e,
                                          const float* __restrict__ W, int jb, float acc[32])
{
    const float4* fr = (const float4*)(src + (long)e * pitch_dw);
    float4 f = fr[0];
    for (int c = 0; c < NC; ++c) {
        float4 fn = fr[c + 1];                 // prefetch next chunk (in-bounds via pitch pad)
        const float* w = &W[(c * 4) * HID + jb];
#pragma unroll
        for (int jj = 0; jj < 32; ++jj) acc[jj] = fmaf(f.x, w[jj],           acc[jj]);
#pragma unroll
        for (int jj = 0; jj < 32; ++jj) acc[jj] = fmaf(f.y, w[HID + jj],     acc[jj]);
#pragma unroll
        for (int jj = 0; jj < 32; ++jj) acc[jj] = fmaf(f.z, w[2 * HID + jj], acc[jj]);
#pragma unroll
        for (int jj = 0; jj < 32; ++jj) acc[jj] = fmaf(f.w, w[3 * HID + jj], acc[jj]);
        f = fn;
    }
}

// ---------------------------------------------------------------- init
__global__ void egnn_init(const float* __restrict__ pos, float* __restrict__ agg,
                          float* __restrict__ outpos)
{
    long i = (long)blockIdx.x * blockDim.x + threadIdx.x;
    if (i < (long)NNODE * HID) agg[i] = 0.0f;
    if (i < (long)NNODE * 3)   outpos[i] = pos[i];
}

// ---------------------------------------------------------------- edge phase (fused MLPs + scatters)
__global__ __launch_bounds__(256)
void egnn_edge(const float* __restrict__ h, const float* __restrict__ pos,
               const float* __restrict__ ea, const int* __restrict__ eidx,
               const float* __restrict__ eW1, const float* __restrict__ eb1,
               const float* __restrict__ eW2, const float* __restrict__ eb2,
               const float* __restrict__ cW1, const float* __restrict__ cb1,
               const float* __restrict__ cW2, const float* __restrict__ cb2,
               float* __restrict__ agg, float* __restrict__ outpos)
{
    __shared__ float feat[EB * PF];     // [e][0..127]=h[row], [128..255]=h[col], [256]=rn, [257]=ea
    __shared__ float bufA[EB * PB];
    __shared__ float rad[EB][4];        // radial xyz + rn
    __shared__ int   rc[2 * EB];        // rows then cols
    __shared__ float partial[EB][4];

    const int t  = threadIdx.x;
    const int e0 = blockIdx.x * EB;

    if (t < 2 * EB) {
        int e = t & (EB - 1);
        rc[t] = (t < EB) ? eidx[e0 + e] : eidx[NEDGE + e0 + e];
    }
    __syncthreads();

    // ---- stage h[row], h[col] (float4 coalesced) + per-edge scalars ----
    for (int i = t; i < EB * 64; i += 256) {
        int e = i >> 6, u = i & 63;
        int n  = (u < 32) ? rc[e] : rc[EB + e];
        int uu = (u < 32) ? u : (u - 32);
        float4 v = *(const float4*)&h[(long)n * HID + uu * 4];
        *(float4*)&feat[e * PF + ((u < 32) ? 0 : HID) + uu * 4] = v;
    }
    if (t < EB) {
        int r = rc[t], c = rc[EB + t];
        float dx = pos[(long)r * 3 + 0] - pos[(long)c * 3 + 0];
        float dy = pos[(long)r * 3 + 1] - pos[(long)c * 3 + 1];
        float dz = pos[(long)r * 3 + 2] - pos[(long)c * 3 + 2];
        float rn = fmaxf(sqrtf(dx * dx + dy * dy + dz * dz), 1e-8f);
        rad[t][0] = dx; rad[t][1] = dy; rad[t][2] = dz; rad[t][3] = rn;
        feat[t * PF + 256] = rn;
        feat[t * PF + 257] = ea[e0 + t];
    }
    __syncthreads();

    const int e  = t & 63;                                            // lane = edge
    const int jb = __builtin_amdgcn_readfirstlane((t >> 6) * 32);     // wave-uniform j-slice
    float acc[32];

    // ---- edge MLP layer 1: [258] @ eW1 -> silu -> bufA ----
#pragma unroll
    for (int jj = 0; jj < 32; ++jj) acc[jj] = eb1[jb + jj];
    panel_fma<64>(feat, PF, e, eW1, jb, acc);
    {
        float frn = feat[e * PF + 256];
        float fev = feat[e * PF + 257];
        const float* w6 = &eW1[256 * HID + jb];
        const float* w7 = &eW1[257 * HID + jb];
#pragma unroll
        for (int jj = 0; jj < 32; ++jj) acc[jj] = fmaf(frn, w6[jj], acc[jj]);
#pragma unroll
        for (int jj = 0; jj < 32; ++jj) acc[jj] = fmaf(fev, w7[jj], acc[jj]);
    }
#pragma unroll
    for (int jj = 0; jj < 32; ++jj) bufA[e * PB + jb + jj] = silu_f(acc[jj]);
    __syncthreads();

    // ---- edge MLP layer 2: bufA @ eW2 -> silu -> m (bufB aliases feat) ----
    float* bufB = feat;   // feat is dead after the barrier above
#pragma unroll
    for (int jj = 0; jj < 32; ++jj) acc[jj] = eb2[jb + jj];
    panel_fma<32>(bufA, PB, e, eW2, jb, acc);
#pragma unroll
    for (int jj = 0; jj < 32; ++jj) bufB[e * PB + jb + jj] = silu_f(acc[jj]);
    __syncthreads();

    // ---- coord MLP layer 1: m @ cW1 -> silu -> bufA ----
#pragma unroll
    for (int jj = 0; jj < 32; ++jj) acc[jj] = cb1[jb + jj];
    panel_fma<32>(bufB, PB, e, cW1, jb, acc);
#pragma unroll
    for (int jj = 0; jj < 32; ++jj) bufA[e * PB + jb + jj] = silu_f(acc[jj]);
    __syncthreads();

    // ---- coord MLP layer 2: dot with cW2 (128->1), 4 partials per edge ----
    {
        float s = 0.0f;
        const float4* fr = (const float4*)&bufA[e * PB + jb];
        const float4* wv = (const float4*)&cW2[jb];     // wave-uniform -> s_load
#pragma unroll
        for (int q = 0; q < 8; ++q) {
            float4 f = fr[q], w = wv[q];
            s += f.x * w.x + f.y * w.y + f.z * w.z + f.w * w.w;
        }
        partial[e][t >> 6] = s;
    }
    __syncthreads();

    // ---- scatter: pos update (3 atomics/edge) + agg (128 atomics/edge) ----
    if (t < EB) {
        float cd  = partial[t][0] + partial[t][1] + partial[t][2] + partial[t][3] + cb2[0];
        float inv = cd / rad[t][3];
        int r = rc[t];
        atomicAdd(&outpos[(long)r * 3 + 0], inv * rad[t][0]);
        atomicAdd(&outpos[(long)r * 3 + 1], inv * rad[t][1]);
        atomicAdd(&outpos[(long)r * 3 + 2], inv * rad[t][2]);
    }
    for (int i = 0; i < (EB * HID) / 256; ++i) {    // 32 iters, per-wave: one edge row, 64 consec j
        int idx = i * 256 + t;
        int ee = idx >> 7, j = idx & 127;
        atomicAdd(&agg[(long)rc[ee] * HID + j], bufB[ee * PB + j]);
    }
}

// ---------------------------------------------------------------- node phase
__global__ __launch_bounds__(256)
void egnn_node(const float* __restrict__ h, const float* __restrict__ agg,
               const float* __restrict__ nW1, const float* __restrict__ nb1,
               const float* __restrict__ nW2, const float* __restrict__ nb2,
               float* __restrict__ out)
{
    __shared__ float feat[EB * PF];     // [n][0..127]=h, [128..255]=agg
    __shared__ float bufA[EB * PB];

    const int t  = threadIdx.x;
    const int n0 = blockIdx.x * EB;

    for (int i = t; i < EB * 64; i += 256) {
        int e = i >> 6, u = i & 63;
        int n = n0 + e; if (n >= NNODE) n = NNODE - 1;  // clamp (compute garbage, stores guarded)
        int uu = (u < 32) ? u : (u - 32);
        float4 v = (u < 32) ? *(const float4*)&h[(long)n * HID + uu * 4]
                            : *(const float4*)&agg[(long)n * HID + uu * 4];
        *(float4*)&feat[e * PF + ((u < 32) ? 0 : HID) + uu * 4] = v;
    }
    __syncthreads();

    const int e  = t & 63;
    const int jb = __builtin_amdgcn_readfirstlane((t >> 6) * 32);
    float acc[32];

    // ---- node MLP layer 1: [256] @ nW1 -> silu -> bufA ----
#pragma unroll
    for (int jj = 0; jj < 32; ++jj) acc[jj] = nb1[jb + jj];
    panel_fma<64>(feat, PF, e, nW1, jb, acc);
#pragma unroll
    for (int jj = 0; jj < 32; ++jj) bufA[e * PB + jb + jj] = silu_f(acc[jj]);
    __syncthreads();

    // ---- node MLP layer 2: bufA @ nW2 -> buf2 (aliases feat) ----
    float* buf2 = feat;
#pragma unroll
    for (int jj = 0; jj < 32; ++jj) acc[jj] = nb2[jb + jj];
    panel_fma<32>(bufA, PB, e, nW2, jb, acc);
#pragma unroll
    for (int jj = 0; jj < 32; ++jj) buf2[e * PB + jb + jj] = acc[jj];
    __syncthreads();

    // ---- residual + coalesced store ----
    for (int i = t; i < EB * 32; i += 256) {
        int e2 = i >> 5, u = i & 31;
        int n = n0 + e2;
        if (n < NNODE) {
            float4 r = *(const float4*)&h[(long)n * HID + u * 4];
            float4 v = *(const float4*)&buf2[e2 * PB + u * 4];
            v.x += r.x; v.y += r.y; v.z += r.z; v.w += r.w;
            *(float4*)&out[(long)n * HID + u * 4] = v;
        }
    }
}

// ---------------------------------------------------------------- launch
extern "C" void kernel_launch(void* const* d_in, const int* in_sizes, int n_in,
                              void* d_out, int out_size, void* d_ws, size_t ws_size,
                              hipStream_t stream)
{
    const float* h    = (const float*)d_in[0];
    const float* pos  = (const float*)d_in[1];
    const float* ea   = (const float*)d_in[2];
    const int*   eidx = (const int*)d_in[3];
    const float* eW1  = (const float*)d_in[4];
    const float* eb1  = (const float*)d_in[5];
    const float* eW2  = (const float*)d_in[6];
    const float* eb2  = (const float*)d_in[7];
    const float* nW1  = (const float*)d_in[8];
    const float* nb1  = (const float*)d_in[9];
    const float* nW2  = (const float*)d_in[10];
    const float* nb2  = (const float*)d_in[11];
    const float* cW1  = (const float*)d_in[12];
    const float* cb1  = (const float*)d_in[13];
    const float* cW2  = (const float*)d_in[14];
    const float* cb2  = (const float*)d_in[15];

    float* out    = (float*)d_out;
    float* outh   = out;                          // [N,128]
    float* outpos = out + (long)NNODE * HID;      // [N,3]
    float* agg    = (float*)d_ws;                 // [N,128] scratch

    egnn_init<<<(NNODE * HID + 255) / 256, 256, 0, stream>>>(pos, agg, outpos);
    egnn_edge<<<NEDGE / EB, 256, 0, stream>>>(h, pos, ea, eidx,
                                              eW1, eb1, eW2, eb2,
                                              cW1, cb1, cW2, cb2,
                                              agg, outpos);
    egnn_node<<<(NNODE + EB - 1) / EB, 256, 0, stream>>>(h, agg, nW1, nb1, nW2, nb2, outh);
}

// Round 2
// 645.624 us; speedup vs baseline: 4.9307x; 4.9307x over previous
//
#include <hip/hip_runtime.h>
#include <math.h>

#define HID   128
#define NNODE 50000
#define NEDGE 800000
#define EB    64
#define P1    296   // edge featA pitch (shorts): >=288, mult of 8 (16B rows)
#define P2    152   // bf16 activation pitch (shorts): >=128, mult of 8
#define PN    392   // node featA pitch (shorts): >=384 (h | agg_hi | agg_lo)

typedef __attribute__((ext_vector_type(8))) short short8;
typedef __attribute__((ext_vector_type(4))) float f32x4;

__device__ __forceinline__ float silu_f(float x) { return x / (1.0f + __expf(-x)); }

__device__ __forceinline__ unsigned short f2bf(float f) {      // RNE
    unsigned int u = __float_as_uint(f);
    u += 0x7FFFu + ((u >> 16) & 1u);
    return (unsigned short)(u >> 16);
}
__device__ __forceinline__ float bf2f(unsigned short s) {
    return __uint_as_float(((unsigned int)s) << 16);
}

// ------------------------------------------------------------------ weight prep
// Frag-major bf16: unit = 16B consumed by one lane for one (ntile,kchunk) frag.
// B[k][n]: n = nt*16 + (lane&15), k = kc*32 + (lane>>4)*8 + j.
// Segments (units of 8 shorts): eW1f@0 (4608, KC=9, Kr=258), eW2f@4608 (2048, KC=4),
// cW1f@6656 (2048, KC=4), nW1f@8704 (6144, KC=12, k>=256 duplicates agg rows for lo-part),
// nW2f@14848 (2048, KC=4). Total 16896 units.
__global__ void egnn_prep(const float* eW1, const float* eW2, const float* cW1,
                          const float* nW1, const float* nW2, short* wsw)
{
    int g = blockIdx.x * 256 + threadIdx.x;
    if (g >= 16896) return;
    const float* src; short* dst; int u, Kr, KC, isN1 = 0;
    if (g < 4608)       { src = eW1; dst = wsw;            u = g;         Kr = 258; KC = 9; }
    else if (g < 6656)  { src = eW2; dst = wsw + 4608*8;   u = g - 4608;  Kr = 128; KC = 4; }
    else if (g < 8704)  { src = cW1; dst = wsw + 6656*8;   u = g - 6656;  Kr = 128; KC = 4; }
    else if (g < 14848) { src = nW1; dst = wsw + 8704*8;   u = g - 8704;  Kr = 384; KC = 12; isN1 = 1; }
    else                { src = nW2; dst = wsw + 14848*8;  u = g - 14848; Kr = 128; KC = 4; }
    int nt   = u / (KC * 64);
    int rem  = u % (KC * 64);
    int kc   = rem >> 6;
    int lane = rem & 63;
    int n    = nt * 16 + (lane & 15);
    int kb   = kc * 32 + ((lane >> 4) & 3) * 8;
    short8 o;
#pragma unroll
    for (int j = 0; j < 8; ++j) {
        int k = kb + j;
        int ks = (isN1 && k >= 256) ? (k - 128) : k;   // agg_lo reuses agg weights
        float v = (k < Kr) ? src[(long)ks * HID + n] : 0.0f;
        o[j] = (short)f2bf(v);
    }
    *(short8*)&dst[(long)u * 8] = o;
}

// ------------------------------------------------------------------ init: zero agg (h_new region), copy pos
__global__ void egnn_init(const float* pos, float* out)
{
    long i = (long)blockIdx.x * 256 + threadIdx.x;
    if (i < (long)NNODE * HID) out[i] = 0.0f;
    if (i < (long)NNODE * 3)   out[(long)NNODE * HID + i] = pos[i];
}

// ------------------------------------------------------------------ edge phase
__global__ __launch_bounds__(256)
void egnn_edge(const float* h, const float* pos, const float* ea, const int* eidx,
               const float* eb1, const float* eb2, const float* cb1,
               const float* cW2, const float* cb2,
               const short* eW1f, const short* eW2f, const short* cW1f,
               float* aggout, float* outpos)
{
    __shared__ __align__(16) short sA[EB * P1];   // 37,888 B : GEMM1 input, then m (pitch P2)
    __shared__ __align__(16) short sB[EB * P2];   // 19,456 B : silu(L1)
    __shared__ int   rci[2 * EB];
    __shared__ float rad[EB][4];
    __shared__ float part[EB][4];

    const int t  = threadIdx.x;
    const int e0 = blockIdx.x * EB;

    if (t < 2 * EB) rci[t] = (t < EB) ? eidx[e0 + t] : eidx[NEDGE + e0 + (t - EB)];
    __syncthreads();

    // ---- stage [h[row] | h[col]] as bf16 ----
    for (int i = t; i < EB * 64; i += 256) {
        int e = i >> 6, u = i & 63;
        int nd = (u < 32) ? rci[e] : rci[EB + e];
        int uu = u & 31;
        const float4 v = *(const float4*)&h[(long)nd * HID + uu * 4];
        unsigned int p0 = f2bf(v.x) | ((unsigned int)f2bf(v.y) << 16);
        unsigned int p1 = f2bf(v.z) | ((unsigned int)f2bf(v.w) << 16);
        *(uint2*)&sA[e * P1 + ((u < 32) ? 0 : HID) + uu * 4] = make_uint2(p0, p1);
    }
    if (t < EB) {
        int r = rci[t], c = rci[EB + t];
        float dx = pos[(long)r * 3 + 0] - pos[(long)c * 3 + 0];
        float dy = pos[(long)r * 3 + 1] - pos[(long)c * 3 + 1];
        float dz = pos[(long)r * 3 + 2] - pos[(long)c * 3 + 2];
        float rn = fmaxf(sqrtf(dx * dx + dy * dy + dz * dz), 1e-8f);
        rad[t][0] = dx; rad[t][1] = dy; rad[t][2] = dz; rad[t][3] = rn;
        sA[t * P1 + 256] = (short)f2bf(rn);
        sA[t * P1 + 257] = (short)f2bf(ea[e0 + t]);
        unsigned int* z = (unsigned int*)sA;     // zero k=258..287 (MFMA pad)
        for (int zz = 0; zz < 15; ++zz) z[148 * t + 129 + zz] = 0u;
    }
    __syncthreads();

    const int lane = t & 63;
    const int w    = t >> 6;          // wave = 32-column n-strip
    const int l15  = lane & 15;
    const int q    = lane >> 4;
    const int ns   = w * 32;

    f32x4 acc[2][4];
    short8 a[4], b[2];

    // ---- GEMM1: [64x288]bf16 @ eW1f -> silu -> sB ----
#pragma unroll
    for (int nt = 0; nt < 2; ++nt) {
        float bv = eb1[ns + nt * 16 + l15];
#pragma unroll
        for (int mt = 0; mt < 4; ++mt)
            for (int r = 0; r < 4; ++r) acc[nt][mt][r] = bv;
    }
    for (int kc = 0; kc < 9; ++kc) {
#pragma unroll
        for (int mt = 0; mt < 4; ++mt)
            a[mt] = *(const short8*)&sA[(mt * 16 + l15) * P1 + kc * 32 + q * 8];
#pragma unroll
        for (int nt = 0; nt < 2; ++nt)
            b[nt] = *(const short8*)&eW1f[(((w * 2 + nt) * 9 + kc) * 64 + lane) * 8];
#pragma unroll
        for (int nt = 0; nt < 2; ++nt)
#pragma unroll
            for (int mt = 0; mt < 4; ++mt)
                acc[nt][mt] = __builtin_amdgcn_mfma_f32_16x16x32_bf16(a[mt], b[nt], acc[nt][mt], 0, 0, 0);
    }
#pragma unroll
    for (int nt = 0; nt < 2; ++nt)
#pragma unroll
        for (int mt = 0; mt < 4; ++mt)
            for (int r = 0; r < 4; ++r)
                sB[(mt * 16 + q * 4 + r) * P2 + ns + nt * 16 + l15] = (short)f2bf(silu_f(acc[nt][mt][r]));
    __syncthreads();

    // ---- GEMM2: sB @ eW2f -> silu = m; atomics to agg (fp32, pre-round) + bf16 m into sA ----
#pragma unroll
    for (int nt = 0; nt < 2; ++nt) {
        float bv = eb2[ns + nt * 16 + l15];
#pragma unroll
        for (int mt = 0; mt < 4; ++mt)
            for (int r = 0; r < 4; ++r) acc[nt][mt][r] = bv;
    }
    for (int kc = 0; kc < 4; ++kc) {
#pragma unroll
        for (int mt = 0; mt < 4; ++mt)
            a[mt] = *(const short8*)&sB[(mt * 16 + l15) * P2 + kc * 32 + q * 8];
#pragma unroll
        for (int nt = 0; nt < 2; ++nt)
            b[nt] = *(const short8*)&eW2f[(((w * 2 + nt) * 4 + kc) * 64 + lane) * 8];
#pragma unroll
        for (int nt = 0; nt < 2; ++nt)
#pragma unroll
            for (int mt = 0; mt < 4; ++mt)
                acc[nt][mt] = __builtin_amdgcn_mfma_f32_16x16x32_bf16(a[mt], b[nt], acc[nt][mt], 0, 0, 0);
    }
    {
        short* sA2 = sA;   // GEMM1 input dead; reuse for m at pitch P2
#pragma unroll
        for (int nt = 0; nt < 2; ++nt)
#pragma unroll
            for (int mt = 0; mt < 4; ++mt)
                for (int r = 0; r < 4; ++r) {
                    float v = silu_f(acc[nt][mt][r]);
                    int m = mt * 16 + q * 4 + r;
                    int n = ns + nt * 16 + l15;
                    atomicAdd(&aggout[(long)rci[m] * HID + n], v);
                    sA2[m * P2 + n] = (short)f2bf(v);
                }
    }
    __syncthreads();

    // ---- GEMM3: m @ cW1f -> silu -> dot(cW2) in fp32 registers ----
#pragma unroll
    for (int nt = 0; nt < 2; ++nt) {
        float bv = cb1[ns + nt * 16 + l15];
#pragma unroll
        for (int mt = 0; mt < 4; ++mt)
            for (int r = 0; r < 4; ++r) acc[nt][mt][r] = bv;
    }
    for (int kc = 0; kc < 4; ++kc) {
#pragma unroll
        for (int mt = 0; mt < 4; ++mt)
            a[mt] = *(const short8*)&sA[(mt * 16 + l15) * P2 + kc * 32 + q * 8];
#pragma unroll
        for (int nt = 0; nt < 2; ++nt)
            b[nt] = *(const short8*)&cW1f[(((w * 2 + nt) * 4 + kc) * 64 + lane) * 8];
#pragma unroll
        for (int nt = 0; nt < 2; ++nt)
#pragma unroll
            for (int mt = 0; mt < 4; ++mt)
                acc[nt][mt] = __builtin_amdgcn_mfma_f32_16x16x32_bf16(a[mt], b[nt], acc[nt][mt], 0, 0, 0);
    }
    {
        float cw0 = cW2[ns + l15];
        float cw1 = cW2[ns + 16 + l15];
#pragma unroll
        for (int mt = 0; mt < 4; ++mt) {
            float p[4];
            for (int r = 0; r < 4; ++r)
                p[r] = silu_f(acc[0][mt][r]) * cw0 + silu_f(acc[1][mt][r]) * cw1;
            for (int mask = 1; mask < 16; mask <<= 1)
                for (int r = 0; r < 4; ++r) p[r] += __shfl_xor(p[r], mask);
            if (l15 == 0)
                for (int r = 0; r < 4; ++r) part[mt * 16 + q * 4 + r][w] = p[r];
        }
    }
    __syncthreads();

    if (t < EB) {
        float cd  = part[t][0] + part[t][1] + part[t][2] + part[t][3] + cb2[0];
        float inv = cd / rad[t][3];
        int r = rci[t];
        atomicAdd(&outpos[(long)r * 3 + 0], inv * rad[t][0]);
        atomicAdd(&outpos[(long)r * 3 + 1], inv * rad[t][1]);
        atomicAdd(&outpos[(long)r * 3 + 2], inv * rad[t][2]);
    }
}

// ------------------------------------------------------------------ node phase
// agg aliases out (h_new region): each block reads only its own rows, then overwrites.
__global__ __launch_bounds__(256)
void egnn_node(const float* h, const float* agg,
               const float* nb1, const float* nb2,
               const short* nW1f, const short* nW2f,
               float* out)
{
    __shared__ __align__(16) short sA[EB * PN];   // 50,176 B : [h | agg_hi | agg_lo]
    __shared__ __align__(16) short sB[EB * P2];   // 19,456 B

    const int t  = threadIdx.x;
    const int n0 = blockIdx.x * EB;

    for (int i = t; i < EB * 64; i += 256) {
        int e = i >> 6, u = i & 63;
        int nd = n0 + e; if (nd >= NNODE) nd = NNODE - 1;
        int uu = u & 31;
        if (u < 32) {
            const float4 v = *(const float4*)&h[(long)nd * HID + uu * 4];
            unsigned int p0 = f2bf(v.x) | ((unsigned int)f2bf(v.y) << 16);
            unsigned int p1 = f2bf(v.z) | ((unsigned int)f2bf(v.w) << 16);
            *(uint2*)&sA[e * PN + uu * 4] = make_uint2(p0, p1);
        } else {
            const float4 v = *(const float4*)&agg[(long)nd * HID + uu * 4];
            unsigned short hx = f2bf(v.x), hy = f2bf(v.y), hz = f2bf(v.z), hw = f2bf(v.w);
            unsigned int p0 = hx | ((unsigned int)hy << 16);
            unsigned int p1 = hz | ((unsigned int)hw << 16);
            *(uint2*)&sA[e * PN + HID + uu * 4] = make_uint2(p0, p1);
            unsigned int l0 = f2bf(v.x - bf2f(hx)) | ((unsigned int)f2bf(v.y - bf2f(hy)) << 16);
            unsigned int l1 = f2bf(v.z - bf2f(hz)) | ((unsigned int)f2bf(v.w - bf2f(hw)) << 16);
            *(uint2*)&sA[e * PN + 2 * HID + uu * 4] = make_uint2(l0, l1);
        }
    }
    __syncthreads();

    const int lane = t & 63;
    const int w    = t >> 6;
    const int l15  = lane & 15;
    const int q    = lane >> 4;
    const int ns   = w * 32;

    f32x4 acc[2][4];
    short8 a[4], b[2];

    // ---- GEMM1: [64x384] @ nW1f -> silu -> sB ----
#pragma unroll
    for (int nt = 0; nt < 2; ++nt) {
        float bv = nb1[ns + nt * 16 + l15];
#pragma unroll
        for (int mt = 0; mt < 4; ++mt)
            for (int r = 0; r < 4; ++r) acc[nt][mt][r] = bv;
    }
    for (int kc = 0; kc < 12; ++kc) {
#pragma unroll
        for (int mt = 0; mt < 4; ++mt)
            a[mt] = *(const short8*)&sA[(mt * 16 + l15) * PN + kc * 32 + q * 8];
#pragma unroll
        for (int nt = 0; nt < 2; ++nt)
            b[nt] = *(const short8*)&nW1f[(((w * 2 + nt) * 12 + kc) * 64 + lane) * 8];
#pragma unroll
        for (int nt = 0; nt < 2; ++nt)
#pragma unroll
            for (int mt = 0; mt < 4; ++mt)
                acc[nt][mt] = __builtin_amdgcn_mfma_f32_16x16x32_bf16(a[mt], b[nt], acc[nt][mt], 0, 0, 0);
    }
#pragma unroll
    for (int nt = 0; nt < 2; ++nt)
#pragma unroll
        for (int mt = 0; mt < 4; ++mt)
            for (int r = 0; r < 4; ++r)
                sB[(mt * 16 + q * 4 + r) * P2 + ns + nt * 16 + l15] = (short)f2bf(silu_f(acc[nt][mt][r]));
    __syncthreads();

    // ---- GEMM2: sB @ nW2f + h residual -> out ----
#pragma unroll
    for (int nt = 0; nt < 2; ++nt) {
        float bv = nb2[ns + nt * 16 + l15];
#pragma unroll
        for (int mt = 0; mt < 4; ++mt)
            for (int r = 0; r < 4; ++r) acc[nt][mt][r] = bv;
    }
    for (int kc = 0; kc < 4; ++kc) {
#pragma unroll
        for (int mt = 0; mt < 4; ++mt)
            a[mt] = *(const short8*)&sB[(mt * 16 + l15) * P2 + kc * 32 + q * 8];
#pragma unroll
        for (int nt = 0; nt < 2; ++nt)
            b[nt] = *(const short8*)&nW2f[(((w * 2 + nt) * 4 + kc) * 64 + lane) * 8];
#pragma unroll
        for (int nt = 0; nt < 2; ++nt)
#pragma unroll
            for (int mt = 0; mt < 4; ++mt)
                acc[nt][mt] = __builtin_amdgcn_mfma_f32_16x16x32_bf16(a[mt], b[nt], acc[nt][mt], 0, 0, 0);
    }
#pragma unroll
    for (int nt = 0; nt < 2; ++nt)
#pragma unroll
        for (int mt = 0; mt < 4; ++mt)
            for (int r = 0; r < 4; ++r) {
                int m  = mt * 16 + q * 4 + r;
                int nd = n0 + m;
                if (nd < NNODE) {
                    int n = ns + nt * 16 + l15;
                    out[(long)nd * HID + n] = h[(long)nd * HID + n] + acc[nt][mt][r];
                }
            }
}

// ------------------------------------------------------------------ launch
extern "C" void kernel_launch(void* const* d_in, const int* in_sizes, int n_in,
                              void* d_out, int out_size, void* d_ws, size_t ws_size,
                              hipStream_t stream)
{
    const float* h    = (const float*)d_in[0];
    const float* pos  = (const float*)d_in[1];
    const float* ea   = (const float*)d_in[2];
    const int*   eidx = (const int*)d_in[3];
    const float* eW1  = (const float*)d_in[4];
    const float* eb1  = (const float*)d_in[5];
    const float* eW2  = (const float*)d_in[6];
    const float* eb2  = (const float*)d_in[7];
    const float* nW1  = (const float*)d_in[8];
    const float* nb1  = (const float*)d_in[9];
    const float* nW2  = (const float*)d_in[10];
    const float* nb2  = (const float*)d_in[11];
    const float* cW1  = (const float*)d_in[12];
    const float* cb1  = (const float*)d_in[13];
    const float* cW2  = (const float*)d_in[14];
    const float* cb2  = (const float*)d_in[15];

    float* out    = (float*)d_out;
    float* outpos = out + (long)NNODE * HID;
    short* wsw    = (short*)d_ws;
    const short* eW1f = wsw;
    const short* eW2f = wsw + 4608 * 8;
    const short* cW1f = wsw + 6656 * 8;
    const short* nW1f = wsw + 8704 * 8;
    const short* nW2f = wsw + 14848 * 8;

    egnn_prep<<<66, 256, 0, stream>>>(eW1, eW2, cW1, nW1, nW2, wsw);
    egnn_init<<<(NNODE * HID + 255) / 256, 256, 0, stream>>>(pos, out);
    egnn_edge<<<NEDGE / EB, 256, 0, stream>>>(h, pos, ea, eidx,
                                              eb1, eb2, cb1, cW2, cb2,
                                              eW1f, eW2f, cW1f, out, outpos);
    egnn_node<<<(NNODE + EB - 1) / EB, 256, 0, stream>>>(h, out, nb1, nb2, nW1f, nW2f, out);
}